// Round 5
// baseline (72.446 us; speedup 1.0000x reference)
//
#include <hip/hip_runtime.h>
#include <hip/hip_bf16.h>

typedef __attribute__((ext_vector_type(8))) __bf16 bf16x8;
typedef __attribute__((ext_vector_type(4))) float f32x4;

__device__ __forceinline__ f32x4 mfma16(bf16x8 a, bf16x8 b, f32x4 c) {
    return __builtin_amdgcn_mfma_f32_16x16x32_bf16(a, b, c, 0, 0, 0);
}

__device__ __forceinline__ unsigned short f2bf(float x) {
    union { float f; unsigned int u; } cv; cv.f = x;
    unsigned int r = cv.u + 0x7FFFu + ((cv.u >> 16) & 1u);
    return (unsigned short)(r >> 16);
}

__device__ __forceinline__ unsigned pack2(float a, float b) {
    return (unsigned)f2bf(a) | ((unsigned)f2bf(b) << 16);
}

__device__ __forceinline__ unsigned pk2(float a, float b) {
    float2 f2; f2.x = a; f2.y = b;
    __hip_bfloat162 h = __float22bfloat162_rn(f2);
    return *(unsigned*)&h;
}

__device__ __forceinline__ float fast_exp2(float x) {
    float r;
    asm("v_exp_f32 %0, %1" : "=v"(r) : "v"(x));
    return r;
}

__device__ __forceinline__ void gload_lds16(const void* g, void* l) {
    __builtin_amdgcn_global_load_lds(
        (const __attribute__((address_space(1))) unsigned int*)g,
        (__attribute__((address_space(3))) unsigned int*)l, 16, 0, 0);
}

// ---------------- Kernel 1: fused weight-norm + q/k transpose ---------------
// z in [0,16): transpose+convert q,k: [B][Cin][S] f32 -> [B][S][Cin] bf16
// z == 16   : weight norm -> bf16 normalized weights
__global__ __launch_bounds__(256) void prep_kernel(
    const float* __restrict__ q, const float* __restrict__ k,
    const float* __restrict__ Wq_v, const float* __restrict__ Wq_g,
    const float* __restrict__ Wk_v, const float* __restrict__ Wk_g,
    const float* __restrict__ Wv_v, const float* __restrict__ Wv_g,
    unsigned short* __restrict__ qT, unsigned short* __restrict__ kT,
    unsigned short* __restrict__ Wn)
{
    __shared__ float tile[32][33];
    int z = blockIdx.z;
    int t = threadIdx.x;
    if (z == 16) {
        int w = t >> 6, lane = t & 63;
        int idx = (blockIdx.y * 32 + blockIdx.x) * 4 + w;   // 0..1535
        int proj = idx >> 9, o = idx & 511;
        const float* v = (proj == 0 ? Wq_v : proj == 1 ? Wk_v : Wv_v) + (size_t)o * 384;
        const float* g = (proj == 0 ? Wq_g : proj == 1 ? Wk_g : Wv_g);
        float vals[6];
        float ss = 0.f;
#pragma unroll
        for (int i = 0; i < 6; ++i) { vals[i] = v[lane + i * 64]; ss += vals[i] * vals[i]; }
#pragma unroll
        for (int off = 1; off < 64; off <<= 1) ss += __shfl_xor(ss, off, 64);
        float scale = g[o] * rsqrtf(ss);
        unsigned short* dst = Wn + ((size_t)proj * 512 + o) * 384;
#pragma unroll
        for (int i = 0; i < 6; ++i) dst[lane + i * 64] = f2bf(vals[i] * scale);
        return;
    }
    int tx = t & 31, ty = t >> 5;
    const float* src = (z < 8 ? q : k) + (size_t)(z & 7) * 384 * 1024;
    unsigned short* dst = (z < 8 ? qT : kT) + (size_t)(z & 7) * 1024 * 384;
    int c0 = blockIdx.y * 32, s0 = blockIdx.x * 32;
#pragma unroll
    for (int j = 0; j < 4; ++j)
        tile[ty + j * 8][tx] = src[(size_t)(c0 + ty + j * 8) * 1024 + s0 + tx];
    __syncthreads();
    int cp = tx & 15;
#pragma unroll
    for (int j = 0; j < 2; ++j) {
        int ss = ty + (tx >> 4) * 8 + j * 16;
        *(unsigned*)&dst[(size_t)(s0 + ss) * 384 + c0 + 2 * cp] =
            pk2(tile[2 * cp][ss], tile[2 * cp + 1][ss]);
    }
}

// ---------------- Kernel 2: projection GEMM (bf16 MFMA, 2-phase pipeline) ---
// Out[b][s][c] = sum_i A[b][s][i] * W[c][i] + bias[c]; M=1024,N=512,K=384
// proj==2 (V) writes its output TRANSPOSED: Vt[b][c][s]
__global__ __launch_bounds__(256) void proj_gemm(
    const unsigned short* __restrict__ qT, const unsigned short* __restrict__ kT,
    const unsigned short* __restrict__ Wn,
    const float* __restrict__ bq, const float* __restrict__ bk, const float* __restrict__ bv,
    unsigned short* __restrict__ Qp, unsigned short* __restrict__ Kp,
    unsigned short* __restrict__ Vt)
{
    __shared__ __align__(16) unsigned short Asm[2][128 * 32];
    __shared__ __align__(16) unsigned short Bsm[2][128 * 32];
    int zb = blockIdx.z; int proj = zb >> 3, b = zb & 7;
    const unsigned short* A = (proj == 0 ? qT : kT) + (size_t)b * 1024 * 384;
    const unsigned short* Bw = Wn + (size_t)proj * 512 * 384;
    const float* bias = proj == 0 ? bq : (proj == 1 ? bk : bv);
    int m0 = blockIdx.x * 128, n0 = blockIdx.y * 128;
    int t = threadIdx.x, w = t >> 6, lane = t & 63;
    int fr = lane & 15, fq = lane >> 4;
    int wm = (w >> 1) * 64, wn = (w & 1) * 64;

    f32x4 acc[4][4];
#pragma unroll
    for (int i = 0; i < 4; ++i)
#pragma unroll
        for (int j = 0; j < 4; ++j) acc[i][j] = (f32x4){0.f, 0.f, 0.f, 0.f};

    const unsigned short* asrc = A + (size_t)(m0 + w * 16 + (lane >> 2)) * 384 + (lane & 3) * 8;
    const unsigned short* bsrc = Bw + (size_t)(n0 + w * 16 + (lane >> 2)) * 384 + (lane & 3) * 8;

    auto stageAB = [&](int k0, int bufi) {
        gload_lds16(asrc + k0, &Asm[bufi][w * 512]);
        gload_lds16(asrc + k0 + (size_t)64 * 384, &Asm[bufi][w * 512 + 2048]);
        gload_lds16(bsrc + k0, &Bsm[bufi][w * 512]);
        gload_lds16(bsrc + k0 + (size_t)64 * 384, &Bsm[bufi][w * 512 + 2048]);
    };

    stageAB(0, 0);
    for (int ks = 0; ks < 12; ++ks) {
        if (ks < 11) {
            stageAB((ks + 1) * 32, (ks + 1) & 1);
            asm volatile("s_waitcnt vmcnt(4)" ::: "memory");
        } else {
            asm volatile("s_waitcnt vmcnt(0)" ::: "memory");
        }
        __builtin_amdgcn_s_barrier();
        int bi = ks & 1;
        bf16x8 af[4], bfr[4];
#pragma unroll
        for (int i = 0; i < 4; ++i)
            af[i] = *(const bf16x8*)&Asm[bi][(wm + i * 16 + fr) * 32 + fq * 8];
#pragma unroll
        for (int i = 0; i < 4; ++i)
            bfr[i] = *(const bf16x8*)&Bsm[bi][(wn + i * 16 + fr) * 32 + fq * 8];
#pragma unroll
        for (int mi = 0; mi < 4; ++mi)
#pragma unroll
            for (int ni = 0; ni < 4; ++ni)
                acc[mi][ni] = mfma16(af[mi], bfr[ni], acc[mi][ni]);
        asm volatile("s_waitcnt lgkmcnt(0)" ::: "memory");
        __builtin_amdgcn_s_barrier();
    }

    if (proj == 2) {
#pragma unroll
        for (int mi = 0; mi < 4; ++mi)
#pragma unroll
            for (int ni = 0; ni < 4; ++ni) {
                int c = n0 + wn + ni * 16 + fr;
                int s0 = m0 + wm + mi * 16 + fq * 4;
                float bc = bias[c];
                unsigned lo = pack2(acc[mi][ni][0] + bc, acc[mi][ni][1] + bc);
                unsigned hi = pack2(acc[mi][ni][2] + bc, acc[mi][ni][3] + bc);
                uint2 u; u.x = lo; u.y = hi;
                *(uint2*)&Vt[(((size_t)b * 512 + c) * 1024 + s0)] = u;
            }
    } else {
        unsigned short* Out = (proj == 0 ? Qp : Kp) + (size_t)b * 1024 * 512;
#pragma unroll
        for (int mi = 0; mi < 4; ++mi)
#pragma unroll
            for (int ni = 0; ni < 4; ++ni)
#pragma unroll
                for (int r = 0; r < 4; ++r) {
                    int c = n0 + wn + ni * 16 + fr;
                    int s = m0 + wm + mi * 16 + fq * 4 + r;
                    Out[(size_t)s * 512 + c] = f2bf(acc[mi][ni][r] + bias[c]);
                }
    }
}

// ---------------- Kernel 3: flash attention, 2 waves x 32q, staged KV -------
// Block: 2 waves x QBLK32 = 64 q-rows; paired q-tiles (j, 15-j) -> 17 units.
// K/V fragments read ONCE per wave, reused across both 16-q column groups
// (halves LDS read traffic vs 16q/wave). Swapped QK^T, log2-domain softmax.
__global__ __launch_bounds__(128, 2) void attn_kernel(
    const unsigned short* __restrict__ Qp, const unsigned short* __restrict__ Kp,
    const unsigned short* __restrict__ Vt, float* __restrict__ out)
{
    __shared__ __align__(16) unsigned short Kl[2][64 * 64];
    __shared__ __align__(16) unsigned short Vl[2][64 * 64];
    __shared__ __align__(16) unsigned short Pl[2][32 * 64];
    const float SCL = 0.125f * 1.44269504089f;   // 1/sqrt(64) * log2(e)
    int pj = blockIdx.x;                          // 0..7
    int bh = blockIdx.y, b = bh >> 3, h = bh & 7;
    int t = threadIdx.x, w = t >> 6, lane = t & 63;
    int fr = lane & 15, fq = lane >> 4;
    int sub = lane >> 3;                        // 0..7
    int sw = 8 * ((lane & 7) ^ sub);            // pre-swizzled source col (shorts)
    int swz = 8 * (fr & 7);                     // read-side XOR (shorts)
    const unsigned short* Qb = Qp + ((size_t)b * 1024) * 512 + h * 64;
    const unsigned short* Kb = Kp + ((size_t)b * 1024) * 512 + h * 64;
    const unsigned short* VTb = Vt + ((size_t)b * 512 + h * 64) * 1024;

    // wave 0 stages K tile (8 x 1KB), wave 1 stages V^T tile (8 x 1KB)
    auto stage = [&](int kt, int bufi) {
        int kbase = kt * 64;
        if (w == 0) {
#pragma unroll
            for (int i = 0; i < 8; ++i)
                gload_lds16(Kb + (size_t)(kbase + i * 8 + sub) * 512 + sw,
                            &Kl[bufi][i * 512]);
        } else {
#pragma unroll
            for (int i = 0; i < 8; ++i)
                gload_lds16(VTb + (size_t)(i * 8 + sub) * 1024 + kbase + sw,
                            &Vl[bufi][i * 512]);
        }
    };

    int cur = 0;
#pragma unroll 1
    for (int ph = 0; ph < 2; ++ph) {
        int qtile = ph == 0 ? pj : 15 - pj;
        int row0 = qtile * 64 + w * 32;
        int nt = qtile + 1;

        bf16x8 qf[2][2];
#pragma unroll
        for (int qg = 0; qg < 2; ++qg)
#pragma unroll
            for (int sl = 0; sl < 2; ++sl)
                qf[qg][sl] = *(const bf16x8*)(Qb + (size_t)(row0 + qg * 16 + fr) * 512 + sl * 32 + fq * 8);

        f32x4 Ot[4][2];
#pragma unroll
        for (int f = 0; f < 4; ++f) { Ot[f][0] = (f32x4){0,0,0,0}; Ot[f][1] = (f32x4){0,0,0,0}; }
        float M[2] = {-128.f, -128.f}, L[2] = {0.f, 0.f};

        stage(0, cur);
        for (int kt = 0; kt < nt; ++kt) {
            int kbase = kt * 64;
            if (kt + 1 < nt) {
                stage(kt + 1, cur ^ 1);
                asm volatile("s_waitcnt vmcnt(8)" ::: "memory");
            } else {
                asm volatile("s_waitcnt vmcnt(0)" ::: "memory");
            }
            __builtin_amdgcn_s_barrier();

            // ---- QK^T (swapped): Sacc[qg][kg] = S[key=kg*16+fq*4+r][q=qg*16+fr]
            f32x4 Sacc[2][4];
#pragma unroll
            for (int kg = 0; kg < 4; ++kg) { Sacc[0][kg] = (f32x4){0,0,0,0}; Sacc[1][kg] = (f32x4){0,0,0,0}; }
#pragma unroll
            for (int kg = 0; kg < 4; ++kg) {
                bf16x8 k0 = *(const bf16x8*)&Kl[cur][(kg * 16 + fr) * 64 + ((fq * 8) ^ swz)];
                bf16x8 k1 = *(const bf16x8*)&Kl[cur][(kg * 16 + fr) * 64 + ((32 + fq * 8) ^ swz)];
                Sacc[0][kg] = mfma16(k0, qf[0][0], Sacc[0][kg]);
                Sacc[0][kg] = mfma16(k1, qf[0][1], Sacc[0][kg]);
                Sacc[1][kg] = mfma16(k0, qf[1][0], Sacc[1][kg]);
                Sacc[1][kg] = mfma16(k1, qf[1][1], Sacc[1][kg]);
            }

            // ---- online softmax per q-group, log2 domain, defer-max THR=8
#pragma unroll
            for (int qg = 0; qg < 2; ++qg) {
                int qrow = row0 + qg * 16 + fr;
                float vmax = -3e38f;
#pragma unroll
                for (int kg = 0; kg < 4; ++kg)
#pragma unroll
                    for (int r = 0; r < 4; ++r) {
                        int key = kbase + kg * 16 + fq * 4 + r;
                        float sv = (key < qrow) ? Sacc[qg][kg][r] * SCL : -3e38f;
                        Sacc[qg][kg][r] = sv;
                        vmax = fmaxf(vmax, sv);
                    }
                vmax = fmaxf(vmax, __shfl_xor(vmax, 16, 64));
                vmax = fmaxf(vmax, __shfl_xor(vmax, 32, 64));
                if (__any(vmax > M[qg] + 8.f)) {
                    float Mn = fmaxf(M[qg], vmax);
                    float al = fast_exp2(M[qg] - Mn);
                    L[qg] *= al;
                    M[qg] = Mn;
#pragma unroll
                    for (int f = 0; f < 4; ++f) {
                        Ot[f][qg][0] *= al; Ot[f][qg][1] *= al;
                        Ot[f][qg][2] *= al; Ot[f][qg][3] *= al;
                    }
                }
                float rs = 0.f;
#pragma unroll
                for (int kg = 0; kg < 4; ++kg) {
                    float e0 = fast_exp2(Sacc[qg][kg][0] - M[qg]);
                    float e1 = fast_exp2(Sacc[qg][kg][1] - M[qg]);
                    float e2 = fast_exp2(Sacc[qg][kg][2] - M[qg]);
                    float e3 = fast_exp2(Sacc[qg][kg][3] - M[qg]);
                    rs += (e0 + e1) + (e2 + e3);
                    uint2 u;
                    u.x = pk2(e0, e1);
                    u.y = pk2(e2, e3);
                    *(uint2*)&Pl[w][(qg * 16 + fr) * 64 + ((kg * 16 + fq * 4) ^ swz)] = u;
                }
                rs += __shfl_xor(rs, 16, 64);
                rs += __shfl_xor(rs, 32, 64);
                L[qg] += rs;
            }

            // ---- PV: O^T += V^T x P (V-frags read once, used for both qg)
            bf16x8 pb[2][2];
#pragma unroll
            for (int qg = 0; qg < 2; ++qg)
#pragma unroll
                for (int sl = 0; sl < 2; ++sl)
                    pb[qg][sl] = *(const bf16x8*)&Pl[w][(qg * 16 + fr) * 64 + ((sl * 32 + fq * 8) ^ swz)];
#pragma unroll
            for (int f = 0; f < 4; ++f) {
                bf16x8 a0 = *(const bf16x8*)&Vl[cur][(f * 16 + fr) * 64 + ((fq * 8) ^ swz)];
                bf16x8 a1 = *(const bf16x8*)&Vl[cur][(f * 16 + fr) * 64 + ((32 + fq * 8) ^ swz)];
                Ot[f][0] = mfma16(a0, pb[0][0], Ot[f][0]);
                Ot[f][0] = mfma16(a1, pb[0][1], Ot[f][0]);
                Ot[f][1] = mfma16(a0, pb[1][0], Ot[f][1]);
                Ot[f][1] = mfma16(a1, pb[1][1], Ot[f][1]);
            }

            asm volatile("s_waitcnt lgkmcnt(0)" ::: "memory");
            __builtin_amdgcn_s_barrier();
            cur ^= 1;
        }

        // ---- epilogue: out[b][h*64+d][q], coalesced along q=fr
#pragma unroll
        for (int qg = 0; qg < 2; ++qg) {
            float rcp = (L[qg] > 0.f) ? 1.f / L[qg] : 0.f;
            int q = row0 + qg * 16 + fr;
#pragma unroll
            for (int f = 0; f < 4; ++f)
#pragma unroll
                for (int rr = 0; rr < 4; ++rr) {
                    int d = f * 16 + fq * 4 + rr;
                    out[((size_t)b * 512 + h * 64 + d) * 1024 + q] = Ot[f][qg][rr] * rcp;
                }
        }
    }
}

extern "C" void kernel_launch(void* const* d_in, const int* in_sizes, int n_in,
                              void* d_out, int out_size, void* d_ws, size_t ws_size,
                              hipStream_t stream) {
    const float* q    = (const float*)d_in[0];
    const float* k    = (const float*)d_in[1];
    const float* Wq_v = (const float*)d_in[2];
    const float* Wq_g = (const float*)d_in[3];
    const float* bq   = (const float*)d_in[4];
    const float* Wk_v = (const float*)d_in[5];
    const float* Wk_g = (const float*)d_in[6];
    const float* bk   = (const float*)d_in[7];
    const float* Wv_v = (const float*)d_in[8];
    const float* Wv_g = (const float*)d_in[9];
    const float* bv   = (const float*)d_in[10];
    float* out = (float*)d_out;

    char* ws = (char*)d_ws;
    unsigned short* qT = (unsigned short*)(ws + 0);                  // 8*1024*384 bf16
    unsigned short* kT = (unsigned short*)(ws + 6291456);
    unsigned short* Wn = (unsigned short*)(ws + 12582912);           // 3*512*384 bf16
    unsigned short* Qp = (unsigned short*)(ws + 13762560);           // 8*1024*512 bf16
    unsigned short* Kp = (unsigned short*)(ws + 22151168);
    unsigned short* Vt = (unsigned short*)(ws + 30539776);           // [b][c][s]

    prep_kernel<<<dim3(32, 12, 17), dim3(256), 0, stream>>>(
        q, k, Wq_v, Wq_g, Wk_v, Wk_g, Wv_v, Wv_g, qT, kT, Wn);
    proj_gemm<<<dim3(8, 4, 24), dim3(256), 0, stream>>>(qT, kT, Wn, bq, bk, bv, Qp, Kp, Vt);
    attn_kernel<<<dim3(8, 64), dim3(128), 0, stream>>>(Qp, Kp, Vt, out);
}

// Round 6
// 70.917 us; speedup vs baseline: 1.0216x; 1.0216x over previous
//
#include <hip/hip_runtime.h>
#include <hip/hip_bf16.h>

typedef __attribute__((ext_vector_type(8))) __bf16 bf16x8;
typedef __attribute__((ext_vector_type(4))) float f32x4;

__device__ __forceinline__ f32x4 mfma16(bf16x8 a, bf16x8 b, f32x4 c) {
    return __builtin_amdgcn_mfma_f32_16x16x32_bf16(a, b, c, 0, 0, 0);
}

__device__ __forceinline__ unsigned short f2bf(float x) {
    union { float f; unsigned int u; } cv; cv.f = x;
    unsigned int r = cv.u + 0x7FFFu + ((cv.u >> 16) & 1u);
    return (unsigned short)(r >> 16);
}

__device__ __forceinline__ unsigned pack2(float a, float b) {
    return (unsigned)f2bf(a) | ((unsigned)f2bf(b) << 16);
}

__device__ __forceinline__ unsigned pk2(float a, float b) {
    float2 f2; f2.x = a; f2.y = b;
    __hip_bfloat162 h = __float22bfloat162_rn(f2);
    return *(unsigned*)&h;
}

__device__ __forceinline__ float fast_exp2(float x) {
    float r;
    asm("v_exp_f32 %0, %1" : "=v"(r) : "v"(x));
    return r;
}

// swap a[32:63] <-> b[0:31]
__device__ __forceinline__ void permswap32(unsigned &a, unsigned &b) {
    asm("v_permlane32_swap_b32 %0, %1" : "+v"(a), "+v"(b));
}
// swap a[16:31]<->b[0:15], a[48:63]<->b[32:47]
__device__ __forceinline__ void permswap16(unsigned &a, unsigned &b) {
    asm("v_permlane16_swap_b32 %0, %1" : "+v"(a), "+v"(b));
}

__device__ __forceinline__ void gload_lds16(const void* g, void* l) {
    __builtin_amdgcn_global_load_lds(
        (const __attribute__((address_space(1))) unsigned int*)g,
        (__attribute__((address_space(3))) unsigned int*)l, 16, 0, 0);
}

// ---------------- Kernel 1: fused weight-norm + q/k transpose ---------------
__global__ __launch_bounds__(256) void prep_kernel(
    const float* __restrict__ q, const float* __restrict__ k,
    const float* __restrict__ Wq_v, const float* __restrict__ Wq_g,
    const float* __restrict__ Wk_v, const float* __restrict__ Wk_g,
    const float* __restrict__ Wv_v, const float* __restrict__ Wv_g,
    unsigned short* __restrict__ qT, unsigned short* __restrict__ kT,
    unsigned short* __restrict__ Wn)
{
    __shared__ float tile[32][33];
    int z = blockIdx.z;
    int t = threadIdx.x;
    if (z == 16) {
        int w = t >> 6, lane = t & 63;
        int idx = (blockIdx.y * 32 + blockIdx.x) * 4 + w;   // 0..1535
        int proj = idx >> 9, o = idx & 511;
        const float* v = (proj == 0 ? Wq_v : proj == 1 ? Wk_v : Wv_v) + (size_t)o * 384;
        const float* g = (proj == 0 ? Wq_g : proj == 1 ? Wk_g : Wv_g);
        float vals[6];
        float ss = 0.f;
#pragma unroll
        for (int i = 0; i < 6; ++i) { vals[i] = v[lane + i * 64]; ss += vals[i] * vals[i]; }
#pragma unroll
        for (int off = 1; off < 64; off <<= 1) ss += __shfl_xor(ss, off, 64);
        float scale = g[o] * rsqrtf(ss);
        unsigned short* dst = Wn + ((size_t)proj * 512 + o) * 384;
#pragma unroll
        for (int i = 0; i < 6; ++i) dst[lane + i * 64] = f2bf(vals[i] * scale);
        return;
    }
    int tx = t & 31, ty = t >> 5;
    const float* src = (z < 8 ? q : k) + (size_t)(z & 7) * 384 * 1024;
    unsigned short* dst = (z < 8 ? qT : kT) + (size_t)(z & 7) * 1024 * 384;
    int c0 = blockIdx.y * 32, s0 = blockIdx.x * 32;
#pragma unroll
    for (int j = 0; j < 4; ++j)
        tile[ty + j * 8][tx] = src[(size_t)(c0 + ty + j * 8) * 1024 + s0 + tx];
    __syncthreads();
    int cp = tx & 15;
#pragma unroll
    for (int j = 0; j < 2; ++j) {
        int ss = ty + (tx >> 4) * 8 + j * 16;
        *(unsigned*)&dst[(size_t)(s0 + ss) * 384 + c0 + 2 * cp] =
            pk2(tile[2 * cp][ss], tile[2 * cp + 1][ss]);
    }
}

// ---------------- Kernel 2: projection GEMM (bf16 MFMA, 2-phase pipeline) ---
__global__ __launch_bounds__(256) void proj_gemm(
    const unsigned short* __restrict__ qT, const unsigned short* __restrict__ kT,
    const unsigned short* __restrict__ Wn,
    const float* __restrict__ bq, const float* __restrict__ bk, const float* __restrict__ bv,
    unsigned short* __restrict__ Qp, unsigned short* __restrict__ Kp,
    unsigned short* __restrict__ Vt)
{
    __shared__ __align__(16) unsigned short Asm[2][128 * 32];
    __shared__ __align__(16) unsigned short Bsm[2][128 * 32];
    int zb = blockIdx.z; int proj = zb >> 3, b = zb & 7;
    const unsigned short* A = (proj == 0 ? qT : kT) + (size_t)b * 1024 * 384;
    const unsigned short* Bw = Wn + (size_t)proj * 512 * 384;
    const float* bias = proj == 0 ? bq : (proj == 1 ? bk : bv);
    int m0 = blockIdx.x * 128, n0 = blockIdx.y * 128;
    int t = threadIdx.x, w = t >> 6, lane = t & 63;
    int fr = lane & 15, fq = lane >> 4;
    int wm = (w >> 1) * 64, wn = (w & 1) * 64;

    f32x4 acc[4][4];
#pragma unroll
    for (int i = 0; i < 4; ++i)
#pragma unroll
        for (int j = 0; j < 4; ++j) acc[i][j] = (f32x4){0.f, 0.f, 0.f, 0.f};

    const unsigned short* asrc = A + (size_t)(m0 + w * 16 + (lane >> 2)) * 384 + (lane & 3) * 8;
    const unsigned short* bsrc = Bw + (size_t)(n0 + w * 16 + (lane >> 2)) * 384 + (lane & 3) * 8;

    auto stageAB = [&](int k0, int bufi) {
        gload_lds16(asrc + k0, &Asm[bufi][w * 512]);
        gload_lds16(asrc + k0 + (size_t)64 * 384, &Asm[bufi][w * 512 + 2048]);
        gload_lds16(bsrc + k0, &Bsm[bufi][w * 512]);
        gload_lds16(bsrc + k0 + (size_t)64 * 384, &Bsm[bufi][w * 512 + 2048]);
    };

    stageAB(0, 0);
    for (int ks = 0; ks < 12; ++ks) {
        if (ks < 11) {
            stageAB((ks + 1) * 32, (ks + 1) & 1);
            asm volatile("s_waitcnt vmcnt(4)" ::: "memory");
        } else {
            asm volatile("s_waitcnt vmcnt(0)" ::: "memory");
        }
        __builtin_amdgcn_s_barrier();
        int bi = ks & 1;
        bf16x8 af[4], bfr[4];
#pragma unroll
        for (int i = 0; i < 4; ++i)
            af[i] = *(const bf16x8*)&Asm[bi][(wm + i * 16 + fr) * 32 + fq * 8];
#pragma unroll
        for (int i = 0; i < 4; ++i)
            bfr[i] = *(const bf16x8*)&Bsm[bi][(wn + i * 16 + fr) * 32 + fq * 8];
#pragma unroll
        for (int mi = 0; mi < 4; ++mi)
#pragma unroll
            for (int ni = 0; ni < 4; ++ni)
                acc[mi][ni] = mfma16(af[mi], bfr[ni], acc[mi][ni]);
        asm volatile("s_waitcnt lgkmcnt(0)" ::: "memory");
        __builtin_amdgcn_s_barrier();
    }

    if (proj == 2) {
#pragma unroll
        for (int mi = 0; mi < 4; ++mi)
#pragma unroll
            for (int ni = 0; ni < 4; ++ni) {
                int c = n0 + wn + ni * 16 + fr;
                int s0 = m0 + wm + mi * 16 + fq * 4;
                float bc = bias[c];
                unsigned lo = pack2(acc[mi][ni][0] + bc, acc[mi][ni][1] + bc);
                unsigned hi = pack2(acc[mi][ni][2] + bc, acc[mi][ni][3] + bc);
                uint2 u; u.x = lo; u.y = hi;
                *(uint2*)&Vt[(((size_t)b * 512 + c) * 1024 + s0)] = u;
            }
    } else {
        unsigned short* Out = (proj == 0 ? Qp : Kp) + (size_t)b * 1024 * 512;
#pragma unroll
        for (int mi = 0; mi < 4; ++mi)
#pragma unroll
            for (int ni = 0; ni < 4; ++ni)
#pragma unroll
                for (int r = 0; r < 4; ++r) {
                    int c = n0 + wn + ni * 16 + fr;
                    int s = m0 + wm + mi * 16 + fq * 4 + r;
                    Out[(size_t)s * 512 + c] = f2bf(acc[mi][ni][r] + bias[c]);
                }
    }
}

// ---------------- Kernel 3: flash attention, kv-split waves, barrier-free ---
// Block = 4 waves, all covering the SAME 64 q-rows; wave w owns kv-tiles
// {w, w+4, ...} of 32 keys (private LDS dbuf, no barriers in main loop).
// Swapped QK^T; P stays in registers via cvt_pk + permlane32/16_swap.
// End of phase: 2-barrier merge of 4 partial (M,L,O) states; wave w merges
// q-group w and writes output. Paired q-tiles (j, 15-j) for balance.
__global__ __launch_bounds__(256, 2) void attn_kernel(
    const unsigned short* __restrict__ Qp, const unsigned short* __restrict__ Kp,
    const unsigned short* __restrict__ Vt, float* __restrict__ out)
{
    __shared__ __align__(16) unsigned short KV[4][2][4096];  // [wave][buf][K 2048 | V 2048]
    __shared__ __align__(16) float MLs[4][4][16][2];         // [wave][qg][fr][{M,L}]
    const float SCL = 0.125f * 1.44269504089f;   // 1/sqrt(64) * log2(e)
    int pj = blockIdx.x;                          // 0..7
    int bh = blockIdx.y, b = bh >> 3, h = bh & 7;
    int tid = threadIdx.x, w = tid >> 6, lane = tid & 63;
    int fr = lane & 15, fq = lane >> 4;
    int swK = 8 * ((lane & 7) ^ (lane >> 3));          // K stage pre-swizzle (shorts)
    int swV = 8 * ((lane & 3) ^ ((lane >> 2) & 3));    // V stage pre-swizzle (shorts)
    const unsigned short* Qb = Qp + ((size_t)b * 1024) * 512 + h * 64;
    const unsigned short* Kb = Kp + ((size_t)b * 1024) * 512 + h * 64;
    const unsigned short* VTb = Vt + ((size_t)b * 512 + h * 64) * 1024;
    float* Osc = (float*)&KV[0][0][0];            // merge scratch overlays KV

    auto stage = [&](int t, int bufi) {
        int kbase = t * 32;
        unsigned short* kb = &KV[w][bufi][0];
        unsigned short* vb = &KV[w][bufi][2048];
#pragma unroll
        for (int i = 0; i < 4; ++i)
            gload_lds16(Kb + (size_t)(kbase + i * 8 + (lane >> 3)) * 512 + swK, kb + i * 512);
#pragma unroll
        for (int i = 0; i < 4; ++i)
            gload_lds16(VTb + (size_t)(i * 16 + (lane >> 2)) * 1024 + kbase + swV, vb + i * 512);
    };

#pragma unroll 1
    for (int ph = 0; ph < 2; ++ph) {
        int qtile = ph == 0 ? pj : 15 - pj;
        int row0 = qtile * 64;
        int ntile = 2 * qtile + 2;                // 32-key tiles

        bf16x8 qf[4][2];
#pragma unroll
        for (int qg = 0; qg < 4; ++qg)
#pragma unroll
            for (int sl = 0; sl < 2; ++sl)
                qf[qg][sl] = *(const bf16x8*)(Qb + (size_t)(row0 + qg * 16 + fr) * 512 + sl * 32 + fq * 8);

        f32x4 Ot[4][4];   // [d-group f][qg]
#pragma unroll
        for (int f = 0; f < 4; ++f)
#pragma unroll
            for (int qg = 0; qg < 4; ++qg) Ot[f][qg] = (f32x4){0.f, 0.f, 0.f, 0.f};
        float M[4] = {-128.f, -128.f, -128.f, -128.f};
        float L[4] = {0.f, 0.f, 0.f, 0.f};

        int buf = 0;
        if (w < ntile) stage(w, 0);
#pragma unroll 1
        for (int t = w; t < ntile; t += 4) {
            if (t + 4 < ntile) {
                stage(t + 4, buf ^ 1);
                asm volatile("s_waitcnt vmcnt(8)" ::: "memory");
            } else {
                asm volatile("s_waitcnt vmcnt(0)" ::: "memory");
            }
            __builtin_amdgcn_sched_barrier(0);
            const unsigned short* kb = &KV[w][buf][0];
            const unsigned short* vb = &KV[w][buf][2048];
            int kbase = t * 32;

            // ---- fragments from private LDS (swizzled, bank-uniform)
            bf16x8 kf[2][2];
#pragma unroll
            for (int kg = 0; kg < 2; ++kg)
#pragma unroll
                for (int sl = 0; sl < 2; ++sl)
                    kf[kg][sl] = *(const bf16x8*)&kb[(kg * 16 + fr) * 64 + (((sl * 4 + fq) ^ (fr & 7)) * 8)];
            bf16x8 vf[4];
#pragma unroll
            for (int f = 0; f < 4; ++f)
                vf[f] = *(const bf16x8*)&vb[(f * 16 + fr) * 32 + ((fq ^ (fr & 3)) * 8)];

            // ---- QK^T (swapped): Sacc[qg][kg], D[key=kg*16+fq*4+r][q=fr]
            f32x4 Sacc[4][2];
#pragma unroll
            for (int qg = 0; qg < 4; ++qg) {
                Sacc[qg][0] = (f32x4){0.f, 0.f, 0.f, 0.f};
                Sacc[qg][1] = (f32x4){0.f, 0.f, 0.f, 0.f};
#pragma unroll
                for (int kg = 0; kg < 2; ++kg) {
                    Sacc[qg][kg] = mfma16(kf[kg][0], qf[qg][0], Sacc[qg][kg]);
                    Sacc[qg][kg] = mfma16(kf[kg][1], qf[qg][1], Sacc[qg][kg]);
                }
            }

            // ---- softmax (log2 domain, defer-max) + in-register P permute + PV
#pragma unroll
            for (int qg = 0; qg < 4; ++qg) {
                int qrow = row0 + qg * 16 + fr;
                float ev[2][4];
                float vmax = -3e38f;
#pragma unroll
                for (int kg = 0; kg < 2; ++kg)
#pragma unroll
                    for (int r = 0; r < 4; ++r) {
                        int key = kbase + kg * 16 + fq * 4 + r;
                        float sv = (key < qrow) ? Sacc[qg][kg][r] * SCL : -3e38f;
                        ev[kg][r] = sv;
                        vmax = fmaxf(vmax, sv);
                    }
                vmax = fmaxf(vmax, __shfl_xor(vmax, 16, 64));
                vmax = fmaxf(vmax, __shfl_xor(vmax, 32, 64));
                if (__any(vmax > M[qg] + 8.f)) {
                    float Mn = fmaxf(M[qg], vmax);
                    float al = fast_exp2(M[qg] - Mn);
                    L[qg] *= al;
                    M[qg] = Mn;
#pragma unroll
                    for (int f = 0; f < 4; ++f) {
                        Ot[f][qg][0] *= al; Ot[f][qg][1] *= al;
                        Ot[f][qg][2] *= al; Ot[f][qg][3] *= al;
                    }
                }
                float rs = 0.f;
#pragma unroll
                for (int kg = 0; kg < 2; ++kg)
#pragma unroll
                    for (int r = 0; r < 4; ++r) {
                        float e = fast_exp2(ev[kg][r] - M[qg]);   // masked -> 0
                        ev[kg][r] = e;
                        rs += e;
                    }
                rs += __shfl_xor(rs, 16, 64);
                rs += __shfl_xor(rs, 32, 64);
                L[qg] += rs;

                // P redistribution: lane holds keys fq*4+r; B-frag needs fq*8+e
                unsigned A0 = pk2(ev[0][0], ev[0][1]);
                unsigned A1 = pk2(ev[0][2], ev[0][3]);
                unsigned B0 = pk2(ev[1][0], ev[1][1]);
                unsigned B1 = pk2(ev[1][2], ev[1][3]);
                permswap32(A0, B0); permswap16(A0, B0);
                permswap32(A1, B1); permswap16(A1, B1);
                union { unsigned u[4]; bf16x8 v; } pu;
                pu.u[0] = A0; pu.u[1] = A1; pu.u[2] = B0; pu.u[3] = B1;
#pragma unroll
                for (int f = 0; f < 4; ++f)
                    Ot[f][qg] = mfma16(vf[f], pu.v, Ot[f][qg]);
            }
            buf ^= 1;
        }

        // ---- write partial state to own scratch region (overlays own KV)
        asm volatile("s_waitcnt vmcnt(0) lgkmcnt(0)" ::: "memory");
#pragma unroll
        for (int qg = 0; qg < 4; ++qg) {
#pragma unroll
            for (int f = 0; f < 4; ++f)
                *(f32x4*)&Osc[(((w * 4 + qg) * 16 + fr) * 64) + (((f * 4 + fq) ^ fr) * 4)] = Ot[f][qg];
            if (fq == 0) { MLs[w][qg][fr][0] = M[qg]; MLs[w][qg][fr][1] = L[qg]; }
        }
        asm volatile("s_waitcnt lgkmcnt(0)" ::: "memory");
        __builtin_amdgcn_s_barrier();

        // ---- merge: wave w handles q-group w across the 4 partials
        float Ms[4], Ls[4];
#pragma unroll
        for (int sv = 0; sv < 4; ++sv) { Ms[sv] = MLs[sv][w][fr][0]; Ls[sv] = MLs[sv][w][fr][1]; }
        float Mmax = fmaxf(fmaxf(Ms[0], Ms[1]), fmaxf(Ms[2], Ms[3]));
        float al[4];
        float Ltot = 0.f;
#pragma unroll
        for (int sv = 0; sv < 4; ++sv) { al[sv] = fast_exp2(Ms[sv] - Mmax); Ltot += al[sv] * Ls[sv]; }
        float rcp = (Ltot > 0.f) ? 1.f / Ltot : 0.f;
        int qcol = row0 + w * 16 + fr;
#pragma unroll
        for (int f = 0; f < 4; ++f) {
            f32x4 accv = (f32x4){0.f, 0.f, 0.f, 0.f};
#pragma unroll
            for (int sv = 0; sv < 4; ++sv) {
                f32x4 o = *(const f32x4*)&Osc[(((sv * 4 + w) * 16 + fr) * 64) + (((f * 4 + fq) ^ fr) * 4)];
                accv[0] += al[sv] * o[0]; accv[1] += al[sv] * o[1];
                accv[2] += al[sv] * o[2]; accv[3] += al[sv] * o[3];
            }
#pragma unroll
            for (int rr = 0; rr < 4; ++rr)
                out[((size_t)b * 512 + h * 64 + f * 16 + fq * 4 + rr) * 1024 + qcol] = accv[rr] * rcp;
        }
        asm volatile("s_waitcnt lgkmcnt(0)" ::: "memory");
        __builtin_amdgcn_s_barrier();    // scratch free before next phase staging
    }
}

extern "C" void kernel_launch(void* const* d_in, const int* in_sizes, int n_in,
                              void* d_out, int out_size, void* d_ws, size_t ws_size,
                              hipStream_t stream) {
    const float* q    = (const float*)d_in[0];
    const float* k    = (const float*)d_in[1];
    const float* Wq_v = (const float*)d_in[2];
    const float* Wq_g = (const float*)d_in[3];
    const float* bq   = (const float*)d_in[4];
    const float* Wk_v = (const float*)d_in[5];
    const float* Wk_g = (const float*)d_in[6];
    const float* bk   = (const float*)d_in[7];
    const float* Wv_v = (const float*)d_in[8];
    const float* Wv_g = (const float*)d_in[9];
    const float* bv   = (const float*)d_in[10];
    float* out = (float*)d_out;

    char* ws = (char*)d_ws;
    unsigned short* qT = (unsigned short*)(ws + 0);                  // 8*1024*384 bf16
    unsigned short* kT = (unsigned short*)(ws + 6291456);
    unsigned short* Wn = (unsigned short*)(ws + 12582912);           // 3*512*384 bf16
    unsigned short* Qp = (unsigned short*)(ws + 13762560);           // 8*1024*512 bf16
    unsigned short* Kp = (unsigned short*)(ws + 22151168);
    unsigned short* Vt = (unsigned short*)(ws + 30539776);           // [b][c][s]

    prep_kernel<<<dim3(32, 12, 17), dim3(256), 0, stream>>>(
        q, k, Wq_v, Wq_g, Wk_v, Wk_g, Wv_v, Wv_g, qT, kT, Wn);
    proj_gemm<<<dim3(8, 4, 24), dim3(256), 0, stream>>>(qT, kT, Wn, bq, bk, bv, Qp, Kp, Vt);
    attn_kernel<<<dim3(8, 64), dim3(256), 0, stream>>>(Qp, Kp, Vt, out);
}

// Round 8
// 65.963 us; speedup vs baseline: 1.0983x; 1.0751x over previous
//
#include <hip/hip_runtime.h>
#include <hip/hip_bf16.h>

typedef __attribute__((ext_vector_type(8))) __bf16 bf16x8;
typedef __attribute__((ext_vector_type(4))) float f32x4;

__device__ __forceinline__ f32x4 mfma16(bf16x8 a, bf16x8 b, f32x4 c) {
    return __builtin_amdgcn_mfma_f32_16x16x32_bf16(a, b, c, 0, 0, 0);
}

__device__ __forceinline__ unsigned short f2bf(float x) {
    union { float f; unsigned int u; } cv; cv.f = x;
    unsigned int r = cv.u + 0x7FFFu + ((cv.u >> 16) & 1u);
    return (unsigned short)(r >> 16);
}

__device__ __forceinline__ unsigned pack2(float a, float b) {
    return (unsigned)f2bf(a) | ((unsigned)f2bf(b) << 16);
}

__device__ __forceinline__ unsigned pk2(float a, float b) {
    float2 f2; f2.x = a; f2.y = b;
    __hip_bfloat162 h = __float22bfloat162_rn(f2);
    return *(unsigned*)&h;
}

__device__ __forceinline__ float fast_exp2(float x) {
    float r;
    asm("v_exp_f32 %0, %1" : "=v"(r) : "v"(x));
    return r;
}

// swap a[32:63] <-> b[0:31]   (safe ONLY when a,b are distinct SSA values;
// identical values get register-coalesced and the swap degenerates)
__device__ __forceinline__ void permswap32(unsigned &a, unsigned &b) {
    asm("v_permlane32_swap_b32 %0, %1" : "+v"(a), "+v"(b));
}
// swap a[16:31]<->b[0:15], a[48:63]<->b[32:47]
__device__ __forceinline__ void permswap16(unsigned &a, unsigned &b) {
    asm("v_permlane16_swap_b32 %0, %1" : "+v"(a), "+v"(b));
}

__device__ __forceinline__ void gload_lds16(const void* g, void* l) {
    __builtin_amdgcn_global_load_lds(
        (const __attribute__((address_space(1))) unsigned int*)g,
        (__attribute__((address_space(3))) unsigned int*)l, 16, 0, 0);
}

// ---------------- Kernel 1: fused weight-norm + q/k transpose ---------------
__global__ __launch_bounds__(256) void prep_kernel(
    const float* __restrict__ q, const float* __restrict__ k,
    const float* __restrict__ Wq_v, const float* __restrict__ Wq_g,
    const float* __restrict__ Wk_v, const float* __restrict__ Wk_g,
    const float* __restrict__ Wv_v, const float* __restrict__ Wv_g,
    unsigned short* __restrict__ qT, unsigned short* __restrict__ kT,
    unsigned short* __restrict__ Wn)
{
    __shared__ float tile[32][33];
    int z = blockIdx.z;
    int t = threadIdx.x;
    if (z == 16) {
        int w = t >> 6, lane = t & 63;
        int idx = (blockIdx.y * 32 + blockIdx.x) * 4 + w;   // 0..1535
        int proj = idx >> 9, o = idx & 511;
        const float* v = (proj == 0 ? Wq_v : proj == 1 ? Wk_v : Wv_v) + (size_t)o * 384;
        const float* g = (proj == 0 ? Wq_g : proj == 1 ? Wk_g : Wv_g);
        float vals[6];
        float ss = 0.f;
#pragma unroll
        for (int i = 0; i < 6; ++i) { vals[i] = v[lane + i * 64]; ss += vals[i] * vals[i]; }
#pragma unroll
        for (int off = 1; off < 64; off <<= 1) ss += __shfl_xor(ss, off, 64);
        float scale = g[o] * rsqrtf(ss);
        unsigned short* dst = Wn + ((size_t)proj * 512 + o) * 384;
#pragma unroll
        for (int i = 0; i < 6; ++i) dst[lane + i * 64] = f2bf(vals[i] * scale);
        return;
    }
    int tx = t & 31, ty = t >> 5;
    const float* src = (z < 8 ? q : k) + (size_t)(z & 7) * 384 * 1024;
    unsigned short* dst = (z < 8 ? qT : kT) + (size_t)(z & 7) * 1024 * 384;
    int c0 = blockIdx.y * 32, s0 = blockIdx.x * 32;
#pragma unroll
    for (int j = 0; j < 4; ++j)
        tile[ty + j * 8][tx] = src[(size_t)(c0 + ty + j * 8) * 1024 + s0 + tx];
    __syncthreads();
    int cp = tx & 15;
#pragma unroll
    for (int j = 0; j < 2; ++j) {
        int ss = ty + (tx >> 4) * 8 + j * 16;
        *(unsigned*)&dst[(size_t)(s0 + ss) * 384 + c0 + 2 * cp] =
            pk2(tile[2 * cp][ss], tile[2 * cp + 1][ss]);
    }
}

// ---------------- Kernel 2: projection GEMM (bf16 MFMA, 2-phase pipeline) ---
// Out[b][s][c] = sum_i A[b][s][i] * W[c][i] + bias[c]; M=1024,N=512,K=384
// proj==2 (V) writes transposed Vt[b][c][s]; proj 0/1 use LDS-repacked
// coalesced 16B stores.
__global__ __launch_bounds__(256) void proj_gemm(
    const unsigned short* __restrict__ qT, const unsigned short* __restrict__ kT,
    const unsigned short* __restrict__ Wn,
    const float* __restrict__ bq, const float* __restrict__ bk, const float* __restrict__ bv,
    unsigned short* __restrict__ Qp, unsigned short* __restrict__ Kp,
    unsigned short* __restrict__ Vt)
{
    __shared__ __align__(16) unsigned short pool[4][128 * 32];   // Asm[2] | Bsm[2]
    int zb = blockIdx.z; int proj = zb >> 3, b = zb & 7;
    const unsigned short* A = (proj == 0 ? qT : kT) + (size_t)b * 1024 * 384;
    const unsigned short* Bw = Wn + (size_t)proj * 512 * 384;
    const float* bias = proj == 0 ? bq : (proj == 1 ? bk : bv);
    int m0 = blockIdx.x * 128, n0 = blockIdx.y * 128;
    int t = threadIdx.x, w = t >> 6, lane = t & 63;
    int fr = lane & 15, fq = lane >> 4;
    int wm = (w >> 1) * 64, wn = (w & 1) * 64;

    f32x4 acc[4][4];
#pragma unroll
    for (int i = 0; i < 4; ++i)
#pragma unroll
        for (int j = 0; j < 4; ++j) acc[i][j] = (f32x4){0.f, 0.f, 0.f, 0.f};

    const unsigned short* asrc = A + (size_t)(m0 + w * 16 + (lane >> 2)) * 384 + (lane & 3) * 8;
    const unsigned short* bsrc = Bw + (size_t)(n0 + w * 16 + (lane >> 2)) * 384 + (lane & 3) * 8;

    auto stageAB = [&](int k0, int bufi) {
        gload_lds16(asrc + k0, &pool[bufi][w * 512]);
        gload_lds16(asrc + k0 + (size_t)64 * 384, &pool[bufi][w * 512 + 2048]);
        gload_lds16(bsrc + k0, &pool[2 + bufi][w * 512]);
        gload_lds16(bsrc + k0 + (size_t)64 * 384, &pool[2 + bufi][w * 512 + 2048]);
    };

    stageAB(0, 0);
    for (int ks = 0; ks < 12; ++ks) {
        if (ks < 11) {
            stageAB((ks + 1) * 32, (ks + 1) & 1);
            asm volatile("s_waitcnt vmcnt(4)" ::: "memory");
        } else {
            asm volatile("s_waitcnt vmcnt(0)" ::: "memory");
        }
        __builtin_amdgcn_s_barrier();
        int bi = ks & 1;
        bf16x8 af[4], bfr[4];
#pragma unroll
        for (int i = 0; i < 4; ++i)
            af[i] = *(const bf16x8*)&pool[bi][(wm + i * 16 + fr) * 32 + fq * 8];
#pragma unroll
        for (int i = 0; i < 4; ++i)
            bfr[i] = *(const bf16x8*)&pool[2 + bi][(wn + i * 16 + fr) * 32 + fq * 8];
#pragma unroll
        for (int mi = 0; mi < 4; ++mi)
#pragma unroll
            for (int ni = 0; ni < 4; ++ni)
                acc[mi][ni] = mfma16(af[mi], bfr[ni], acc[mi][ni]);
        asm volatile("s_waitcnt lgkmcnt(0)" ::: "memory");
        __builtin_amdgcn_s_barrier();
    }

    if (proj == 2) {
#pragma unroll
        for (int mi = 0; mi < 4; ++mi)
#pragma unroll
            for (int ni = 0; ni < 4; ++ni) {
                int c = n0 + wn + ni * 16 + fr;
                int s0 = m0 + wm + mi * 16 + fq * 4;
                float bc = bias[c];
                unsigned lo = pack2(acc[mi][ni][0] + bc, acc[mi][ni][1] + bc);
                unsigned hi = pack2(acc[mi][ni][2] + bc, acc[mi][ni][3] + bc);
                uint2 u; u.x = lo; u.y = hi;
                *(uint2*)&Vt[(((size_t)b * 512 + c) * 1024 + s0)] = u;
            }
    } else {
        unsigned short* Out = (proj == 0 ? Qp : Kp) + (size_t)b * 1024 * 512;
        const int STR = 72;                               // padded row stride (shorts)
        unsigned short* scr = &pool[0][0] + w * 2304;     // 32 x 72 shorts per wave
#pragma unroll
        for (int p = 0; p < 2; ++p) {
#pragma unroll
            for (int mh = 0; mh < 2; ++mh) {
                int mi = p * 2 + mh;
#pragma unroll
                for (int ni = 0; ni < 4; ++ni) {
                    int c = n0 + wn + ni * 16 + fr;
                    float bc = bias[c];
#pragma unroll
                    for (int r = 0; r < 4; ++r)
                        scr[(mh * 16 + fq * 4 + r) * STR + ni * 16 + fr] =
                            f2bf(acc[mi][ni][r] + bc);
                }
            }
            asm volatile("s_waitcnt lgkmcnt(0)" ::: "memory");
            int sp = lane >> 1, ch = (lane & 1) * 32;
            int s = m0 + wm + p * 32 + sp;
#pragma unroll
            for (int kk = 0; kk < 4; ++kk) {
                bf16x8 v = *(const bf16x8*)&scr[sp * STR + ch + 8 * kk];
                *(bf16x8*)&Out[(size_t)s * 512 + n0 + wn + ch + 8 * kk] = v;
            }
            asm volatile("s_waitcnt lgkmcnt(0)" ::: "memory");
        }
    }
}

// ---------------- Kernel 3: flash attention, 4 waves x 16q, KVBLK=128 -------
// R3 skeleton (paired q-tiles j,15-j -> 9 uniform 128-key units/block) with
// in-register P (pk2 + permlane32/16 swaps, no P LDS). Softmax reduces use
// __shfl_xor (permlane variant was register-coalesced into a self-swap: R6 bug).
__global__ __launch_bounds__(256, 2) void attn_kernel(
    const unsigned short* __restrict__ Qp, const unsigned short* __restrict__ Kp,
    const unsigned short* __restrict__ Vt, float* __restrict__ out)
{
    __shared__ __align__(16) unsigned short Kl[2][128 * 64];  // [key][c], swizzled
    __shared__ __align__(16) unsigned short Vl[2][64 * 128];  // [d][key], swizzled
    const float SCL = 0.125f * 1.44269504089f;   // 1/sqrt(64) * log2(e)
    int pj = blockIdx.x;                          // 0..7
    int bh = blockIdx.y, b = bh >> 3, h = bh & 7;
    int tid = threadIdx.x, w = tid >> 6, lane = tid & 63;
    int fr = lane & 15, fq = lane >> 4;
    const unsigned short* Qb = Qp + ((size_t)b * 1024) * 512 + h * 64;
    const unsigned short* Kb = Kp + ((size_t)b * 1024) * 512 + h * 64;
    const unsigned short* VTb = Vt + ((size_t)b * 512 + h * 64) * 1024;
    int f3 = fr & 7;
    int swK = 8 * ((lane & 7) ^ (lane >> 3));     // K stage pre-swizzle (shorts)

    // wave w stages K rows [32w,32w+32) and V^T rows [16w,16w+16)
    auto stage = [&](int kt, int bufi) {
        int kbase = kt * 128;
#pragma unroll
        for (int i = 0; i < 4; ++i) {
            int r0 = w * 32 + i * 8;
            gload_lds16(Kb + (size_t)(kbase + r0 + (lane >> 3)) * 512 + swK,
                        &Kl[bufi][r0 * 64]);
        }
#pragma unroll
        for (int i = 0; i < 4; ++i) {
            int d0 = w * 16 + i * 4;
            int swV = 8 * ((lane & 15) ^ (i * 4 + (lane >> 4)));
            gload_lds16(VTb + (size_t)(d0 + (lane >> 4)) * 1024 + kbase + swV,
                        &Vl[bufi][d0 * 128]);
        }
    };

    int cur = 0;
#pragma unroll 1
    for (int ph = 0; ph < 2; ++ph) {
        int qtile = ph == 0 ? pj : 15 - pj;
        int row0 = qtile * 64 + w * 16;
        int nt = (qtile >> 1) + 1;                // 128-key units

        bf16x8 qf0 = *(const bf16x8*)(Qb + (size_t)(row0 + fr) * 512 + fq * 8);
        bf16x8 qf1 = *(const bf16x8*)(Qb + (size_t)(row0 + fr) * 512 + 32 + fq * 8);

        f32x4 Ot[4];
#pragma unroll
        for (int f = 0; f < 4; ++f) Ot[f] = (f32x4){0.f, 0.f, 0.f, 0.f};
        float M = -128.f, L = 0.f;
        int qrow = row0 + fr;

        stage(0, cur);
        for (int kt = 0; kt < nt; ++kt) {
            int kbase = kt * 128;
            if (kt + 1 < nt) {
                stage(kt + 1, cur ^ 1);
                asm volatile("s_waitcnt vmcnt(8)" ::: "memory");
            } else {
                asm volatile("s_waitcnt vmcnt(0)" ::: "memory");
            }
            __builtin_amdgcn_s_barrier();

            // ---- QK^T (swapped): S[kg] = D[key=kg*16+fq*4+r][q=fr]
            f32x4 S[8];
#pragma unroll
            for (int kg = 0; kg < 8; ++kg) {
                bf16x8 k0 = *(const bf16x8*)&Kl[cur][(kg * 16 + fr) * 64 + ((fq ^ f3) * 8)];
                bf16x8 k1 = *(const bf16x8*)&Kl[cur][(kg * 16 + fr) * 64 + (((4 + fq) ^ f3) * 8)];
                S[kg] = mfma16(k0, qf0, (f32x4){0.f, 0.f, 0.f, 0.f});
                S[kg] = mfma16(k1, qf1, S[kg]);
            }

            // ---- mask + online softmax (log2 domain, defer-max THR=8)
            float vmax = -3e38f;
#pragma unroll
            for (int kg = 0; kg < 8; ++kg)
#pragma unroll
                for (int r = 0; r < 4; ++r) {
                    int key = kbase + kg * 16 + fq * 4 + r;
                    float sv = (key < qrow) ? S[kg][r] * SCL : -3e38f;
                    S[kg][r] = sv;
                    vmax = fmaxf(vmax, sv);
                }
            vmax = fmaxf(vmax, __shfl_xor(vmax, 16, 64));
            vmax = fmaxf(vmax, __shfl_xor(vmax, 32, 64));
            if (__any(vmax > M + 8.f)) {
                float Mn = fmaxf(M, vmax);
                float al = fast_exp2(M - Mn);
                L *= al;
                M = Mn;
#pragma unroll
                for (int f = 0; f < 4; ++f) {
                    Ot[f][0] *= al; Ot[f][1] *= al; Ot[f][2] *= al; Ot[f][3] *= al;
                }
            }
            float rs = 0.f;
#pragma unroll
            for (int kg = 0; kg < 8; ++kg)
#pragma unroll
                for (int r = 0; r < 4; ++r) {
                    float e = fast_exp2(S[kg][r] - M);   // masked -> 0
                    S[kg][r] = e;
                    rs += e;
                }
            rs += __shfl_xor(rs, 16, 64);
            rs += __shfl_xor(rs, 32, 64);
            L += rs;

            // ---- in-register P -> B-frags (per 32-key pair of kg)
            bf16x8 pb[4];
#pragma unroll
            for (int m = 0; m < 4; ++m) {
                unsigned A0 = pk2(S[2 * m][0], S[2 * m][1]);
                unsigned A1 = pk2(S[2 * m][2], S[2 * m][3]);
                unsigned B0 = pk2(S[2 * m + 1][0], S[2 * m + 1][1]);
                unsigned B1 = pk2(S[2 * m + 1][2], S[2 * m + 1][3]);
                permswap32(A0, B0); permswap16(A0, B0);
                permswap32(A1, B1); permswap16(A1, B1);
                union { unsigned u[4]; bf16x8 v; } pu;
                pu.u[0] = A0; pu.u[1] = A1; pu.u[2] = B0; pu.u[3] = B1;
                pb[m] = pu.v;
            }

            // ---- PV: O^T += V^T x P
#pragma unroll
            for (int m = 0; m < 4; ++m)
#pragma unroll
                for (int f = 0; f < 4; ++f) {
                    bf16x8 vf = *(const bf16x8*)&Vl[cur][(f * 16 + fr) * 128 + (((4 * m + fq) ^ fr) * 8)];
                    Ot[f] = mfma16(vf, pb[m], Ot[f]);
                }

            asm volatile("s_waitcnt lgkmcnt(0)" ::: "memory");
            __builtin_amdgcn_s_barrier();
            cur ^= 1;
        }

        // ---- epilogue: out[b][h*64+d][q], coalesced along q=fr
        float rcp = (L > 0.f) ? 1.f / L : 0.f;
        int q = row0 + fr;
#pragma unroll
        for (int f = 0; f < 4; ++f)
#pragma unroll
            for (int rr = 0; rr < 4; ++rr) {
                int d = f * 16 + fq * 4 + rr;
                out[((size_t)b * 512 + h * 64 + d) * 1024 + q] = Ot[f][rr] * rcp;
            }
    }
}

extern "C" void kernel_launch(void* const* d_in, const int* in_sizes, int n_in,
                              void* d_out, int out_size, void* d_ws, size_t ws_size,
                              hipStream_t stream) {
    const float* q    = (const float*)d_in[0];
    const float* k    = (const float*)d_in[1];
    const float* Wq_v = (const float*)d_in[2];
    const float* Wq_g = (const float*)d_in[3];
    const float* bq   = (const float*)d_in[4];
    const float* Wk_v = (const float*)d_in[5];
    const float* Wk_g = (const float*)d_in[6];
    const float* bk   = (const float*)d_in[7];
    const float* Wv_v = (const float*)d_in[8];
    const float* Wv_g = (const float*)d_in[9];
    const float* bv   = (const float*)d_in[10];
    float* out = (float*)d_out;

    char* ws = (char*)d_ws;
    unsigned short* qT = (unsigned short*)(ws + 0);                  // 8*1024*384 bf16
    unsigned short* kT = (unsigned short*)(ws + 6291456);
    unsigned short* Wn = (unsigned short*)(ws + 12582912);           // 3*512*384 bf16
    unsigned short* Qp = (unsigned short*)(ws + 13762560);           // 8*1024*512 bf16
    unsigned short* Kp = (unsigned short*)(ws + 22151168);
    unsigned short* Vt = (unsigned short*)(ws + 30539776);           // [b][c][s]

    prep_kernel<<<dim3(32, 12, 17), dim3(256), 0, stream>>>(
        q, k, Wq_v, Wq_g, Wk_v, Wk_g, Wv_v, Wv_g, qT, kT, Wn);
    proj_gemm<<<dim3(8, 4, 24), dim3(256), 0, stream>>>(qT, kT, Wn, bq, bk, bv, Qp, Kp, Vt);
    attn_kernel<<<dim3(8, 64), dim3(256), 0, stream>>>(Qp, Kp, Vt, out);
}